// Round 4
// baseline (488.602 us; speedup 1.0000x reference)
//
#include <hip/hip_runtime.h>
#include <hip/hip_fp16.h>
#include <hip/hip_cooperative_groups.h>
#include <math.h>
#include <float.h>

namespace cg = cooperative_groups;

#define N_NODES 100000
#define N_EDGES 1200000
#define FEAT 64
#define AVG_D_LOG 2.5649493574615367f  /* log(13.0) */
#define EPS_STD 1e-5f
#define EPS_BN 1e-5
#define RED_BLOCKS 512
#define GRID_MAX 2048
#define HN_BLOCKS 6250                 /* N_NODES*FEAT/4/256 */
#define RP_BLOCKS 391                  /* ceil((N_NODES+1)/256) */

// ============================ fused cooperative kernel ======================
__global__ void __launch_bounds__(256, 8) pna_fused(
    const float* __restrict__ h, const float* __restrict__ norm,
    const float* __restrict__ bnw, const float* __restrict__ bnb,
    const int* __restrict__ src, const int* __restrict__ dst,
    float* __restrict__ out,
    __half* __restrict__ hn, int* __restrict__ rowptr,
    double* __restrict__ psum, double* __restrict__ psumsq,
    float* __restrict__ scale, float* __restrict__ shift)
{
    cg::grid_group grid = cg::this_grid();
    const int tid  = threadIdx.x;
    const int nthr = (int)gridDim.x * 256;
    const int gtid = (int)blockIdx.x * 256 + tid;

    // ---------- phase 0: hn = (half)(h*norm)  +  rowptr ----------
    for (size_t i4 = (size_t)gtid * 4; i4 < (size_t)N_NODES * FEAT; i4 += (size_t)nthr * 4) {
        const int node = (int)(i4 >> 6);
        const float nr = norm[node];
        float4 v = *reinterpret_cast<const float4*>(h + i4);
        __half2 p0 = __floats2half2_rn(v.x * nr, v.y * nr);
        __half2 p1 = __floats2half2_rn(v.z * nr, v.w * nr);
        __half2* o2 = reinterpret_cast<__half2*>(hn + i4);
        o2[0] = p0; o2[1] = p1;
    }
    for (int n = gtid; n <= N_NODES; n += nthr) {
        int lo = 0, hi = N_EDGES;
        while (lo < hi) {
            int mid = (lo + hi) >> 1;
            if (dst[mid] < n) lo = mid + 1; else hi = mid;
        }
        rowptr[n] = lo;
    }
    grid.sync();

    // ---------- phase 1: PNA aggregation + in-register BN partials ----------
    const int wid  = tid >> 6;
    const int lane = tid & 63;
    float accS = 0.f, accQ = 0.f;          // this lane's feature, this wave's nodes

    for (int node = (int)blockIdx.x * 4 + wid; node < N_NODES; node += (int)gridDim.x * 4) {
        const int start = __builtin_amdgcn_readfirstlane(rowptr[node]);
        const int end   = __builtin_amdgcn_readfirstlane(rowptr[node + 1]);
        const int deg   = end - start;

        const float hnv = __half2float(hn[(size_t)node * FEAT + lane]);

        float pre;
        if (deg > 0) {
            float s1a = 0.f, s1b = 0.f, s1c = 0.f, s1d = 0.f;
            float s2a = 0.f, s2b = 0.f, s2c = 0.f, s2d = 0.f;
            float mx = -FLT_MAX, mn = FLT_MAX;
            int e = start;
            for (; e + 8 <= end; e += 8) {
                const int i0 = src[e + 0]; const int i1 = src[e + 1];
                const int i2 = src[e + 2]; const int i3 = src[e + 3];
                const int i4 = src[e + 4]; const int i5 = src[e + 5];
                const int i6 = src[e + 6]; const int i7 = src[e + 7];
                const float v0 = __half2float(hn[(size_t)i0 * FEAT + lane]);
                const float v1 = __half2float(hn[(size_t)i1 * FEAT + lane]);
                const float v2 = __half2float(hn[(size_t)i2 * FEAT + lane]);
                const float v3 = __half2float(hn[(size_t)i3 * FEAT + lane]);
                const float v4 = __half2float(hn[(size_t)i4 * FEAT + lane]);
                const float v5 = __half2float(hn[(size_t)i5 * FEAT + lane]);
                const float v6 = __half2float(hn[(size_t)i6 * FEAT + lane]);
                const float v7 = __half2float(hn[(size_t)i7 * FEAT + lane]);
                s1a += v0; s2a += v0 * v0; mx = fmaxf(mx, v0); mn = fminf(mn, v0);
                s1b += v1; s2b += v1 * v1; mx = fmaxf(mx, v1); mn = fminf(mn, v1);
                s1c += v2; s2c += v2 * v2; mx = fmaxf(mx, v2); mn = fminf(mn, v2);
                s1d += v3; s2d += v3 * v3; mx = fmaxf(mx, v3); mn = fminf(mn, v3);
                s1a += v4; s2a += v4 * v4; mx = fmaxf(mx, v4); mn = fminf(mn, v4);
                s1b += v5; s2b += v5 * v5; mx = fmaxf(mx, v5); mn = fminf(mn, v5);
                s1c += v6; s2c += v6 * v6; mx = fmaxf(mx, v6); mn = fminf(mn, v6);
                s1d += v7; s2d += v7 * v7; mx = fmaxf(mx, v7); mn = fminf(mn, v7);
            }
            if (e + 4 <= end) {
                const int i0 = src[e + 0]; const int i1 = src[e + 1];
                const int i2 = src[e + 2]; const int i3 = src[e + 3];
                const float v0 = __half2float(hn[(size_t)i0 * FEAT + lane]);
                const float v1 = __half2float(hn[(size_t)i1 * FEAT + lane]);
                const float v2 = __half2float(hn[(size_t)i2 * FEAT + lane]);
                const float v3 = __half2float(hn[(size_t)i3 * FEAT + lane]);
                s1a += v0; s2a += v0 * v0; mx = fmaxf(mx, v0); mn = fminf(mn, v0);
                s1b += v1; s2b += v1 * v1; mx = fmaxf(mx, v1); mn = fminf(mn, v1);
                s1c += v2; s2c += v2 * v2; mx = fmaxf(mx, v2); mn = fminf(mn, v2);
                s1d += v3; s2d += v3 * v3; mx = fmaxf(mx, v3); mn = fminf(mn, v3);
                e += 4;
            }
            for (; e < end; ++e) {
                const int s = src[e];
                const float v = __half2float(hn[(size_t)s * FEAT + lane]);
                s1a += v; s2a += v * v; mx = fmaxf(mx, v); mn = fminf(mn, v);
            }
            const float s1 = (s1a + s1b) + (s1c + s1d);
            const float s2 = (s2a + s2b) + (s2c + s2d);

            const float invd = 1.0f / (float)deg;
            const float mean = s1 * invd;
            const float var  = fmaxf(s2 * invd - mean * mean, 0.0f);
            const float stdv = sqrtf(var + EPS_STD);
            const float logD = logf((float)deg + 1.0f);
            const float nrm  = norm[node];
            const float factor = nrm * (1.0f + logD * (1.0f / AVG_D_LOG) + AVG_D_LOG / logD)
                                     * (1.0f / 13.0f);
            pre = hnv * (1.0f / 13.0f) + (mean + mx + mn + stdv) * factor;
        } else {
            pre = hnv * (1.0f / 13.0f);
        }
        const float val = fmaxf(pre, 0.0f);
        out[(size_t)node * FEAT + lane] = val;
        accS += val;
        accQ += val * val;
    }

    __shared__ float lsS[256], lsQ[256];
    lsS[tid] = accS; lsQ[tid] = accQ;
    __syncthreads();
    if (tid < 64) {
        double S = (double)lsS[tid] + (double)lsS[tid + 64]
                 + (double)lsS[tid + 128] + (double)lsS[tid + 192];
        double Q = (double)lsQ[tid] + (double)lsQ[tid + 64]
                 + (double)lsQ[tid + 128] + (double)lsQ[tid + 192];
        psum  [(size_t)blockIdx.x * 64 + tid] = S;
        psumsq[(size_t)blockIdx.x * 64 + tid] = Q;
    }
    grid.sync();

    // ---------- phase 2: reduce partials -> scale/shift (blocks 0..63) ------
    if (blockIdx.x < 64) {
        const int f = (int)blockIdx.x;
        double S = 0.0, Q = 0.0;
        for (int b = tid; b < (int)gridDim.x; b += 256) {
            S += psum  [(size_t)b * 64 + f];
            Q += psumsq[(size_t)b * 64 + f];
        }
        __shared__ double rs[256], rq[256];
        rs[tid] = S; rq[tid] = Q;
        __syncthreads();
        for (int s = 128; s > 0; s >>= 1) {
            if (tid < s) { rs[tid] += rs[tid + s]; rq[tid] += rq[tid + s]; }
            __syncthreads();
        }
        if (tid == 0) {
            double mu   = rs[0] / (double)N_NODES;
            double var  = rq[0] / (double)N_NODES - mu * mu;
            double rstd = 1.0 / sqrt(var + EPS_BN);
            float sc = (float)rstd * bnw[f];
            scale[f] = sc;
            shift[f] = bnb[f] - (float)mu * sc;
        }
    }
    grid.sync();

    // ---------- phase 3: BN apply ----------
    __shared__ float sS[64], sH[64];
    if (tid < 64) { sS[tid] = scale[tid]; sH[tid] = shift[tid]; }
    __syncthreads();
    for (size_t i4 = (size_t)gtid * 4; i4 < (size_t)N_NODES * FEAT; i4 += (size_t)nthr * 4) {
        float4 v = *reinterpret_cast<const float4*>(out + i4);
        const int f = (int)(i4 & 63);
        v.x = v.x * sS[f + 0] + sH[f + 0];
        v.y = v.y * sS[f + 1] + sH[f + 1];
        v.z = v.z * sS[f + 2] + sH[f + 2];
        v.w = v.w * sS[f + 3] + sH[f + 3];
        *reinterpret_cast<float4*>(out + i4) = v;
    }
}

// ============================ fallback multi-kernel path ====================
__global__ void __launch_bounds__(256) hn_rowptr(
    const float* __restrict__ h, const float* __restrict__ norm,
    const int* __restrict__ dst,
    __half* __restrict__ hn_h, int* __restrict__ rowptr)
{
    const int b = blockIdx.x;
    if (b < HN_BLOCKS) {
        const size_t i4 = ((size_t)b * 256 + threadIdx.x) * 4;
        const int node = (int)(i4 >> 6);
        const float nr = norm[node];
        float4 v = *reinterpret_cast<const float4*>(h + i4);
        __half2 p0 = __floats2half2_rn(v.x * nr, v.y * nr);
        __half2 p1 = __floats2half2_rn(v.z * nr, v.w * nr);
        __half2* o = reinterpret_cast<__half2*>(hn_h + i4);
        o[0] = p0; o[1] = p1;
    } else {
        const int n = (b - HN_BLOCKS) * 256 + threadIdx.x;
        if (n > N_NODES) return;
        int lo = 0, hi = N_EDGES;
        while (lo < hi) {
            int mid = (lo + hi) >> 1;
            if (dst[mid] < n) lo = mid + 1; else hi = mid;
        }
        rowptr[n] = lo;
    }
}

__global__ void __launch_bounds__(256) pna_agg_fast(
    const __half* __restrict__ hn, const float* __restrict__ norm,
    const int* __restrict__ src, const int* __restrict__ rowptr,
    float* __restrict__ out1)
{
    const int wid  = threadIdx.x >> 6;
    const int lane = threadIdx.x & 63;
    const int node = blockIdx.x * 4 + wid;
    if (node >= N_NODES) return;

    const int start = __builtin_amdgcn_readfirstlane(rowptr[node]);
    const int end   = __builtin_amdgcn_readfirstlane(rowptr[node + 1]);
    const int deg   = end - start;
    const float hnv = __half2float(hn[(size_t)node * FEAT + lane]);

    float pre;
    if (deg > 0) {
        float s1a = 0.f, s1b = 0.f, s1c = 0.f, s1d = 0.f;
        float s2a = 0.f, s2b = 0.f, s2c = 0.f, s2d = 0.f;
        float mx = -FLT_MAX, mn = FLT_MAX;
        int e = start;
        for (; e + 8 <= end; e += 8) {
            const int i0 = src[e + 0]; const int i1 = src[e + 1];
            const int i2 = src[e + 2]; const int i3 = src[e + 3];
            const int i4 = src[e + 4]; const int i5 = src[e + 5];
            const int i6 = src[e + 6]; const int i7 = src[e + 7];
            const float v0 = __half2float(hn[(size_t)i0 * FEAT + lane]);
            const float v1 = __half2float(hn[(size_t)i1 * FEAT + lane]);
            const float v2 = __half2float(hn[(size_t)i2 * FEAT + lane]);
            const float v3 = __half2float(hn[(size_t)i3 * FEAT + lane]);
            const float v4 = __half2float(hn[(size_t)i4 * FEAT + lane]);
            const float v5 = __half2float(hn[(size_t)i5 * FEAT + lane]);
            const float v6 = __half2float(hn[(size_t)i6 * FEAT + lane]);
            const float v7 = __half2float(hn[(size_t)i7 * FEAT + lane]);
            s1a += v0; s2a += v0 * v0; mx = fmaxf(mx, v0); mn = fminf(mn, v0);
            s1b += v1; s2b += v1 * v1; mx = fmaxf(mx, v1); mn = fminf(mn, v1);
            s1c += v2; s2c += v2 * v2; mx = fmaxf(mx, v2); mn = fminf(mn, v2);
            s1d += v3; s2d += v3 * v3; mx = fmaxf(mx, v3); mn = fminf(mn, v3);
            s1a += v4; s2a += v4 * v4; mx = fmaxf(mx, v4); mn = fminf(mn, v4);
            s1b += v5; s2b += v5 * v5; mx = fmaxf(mx, v5); mn = fminf(mn, v5);
            s1c += v6; s2c += v6 * v6; mx = fmaxf(mx, v6); mn = fminf(mn, v6);
            s1d += v7; s2d += v7 * v7; mx = fmaxf(mx, v7); mn = fminf(mn, v7);
        }
        if (e + 4 <= end) {
            const int i0 = src[e + 0]; const int i1 = src[e + 1];
            const int i2 = src[e + 2]; const int i3 = src[e + 3];
            const float v0 = __half2float(hn[(size_t)i0 * FEAT + lane]);
            const float v1 = __half2float(hn[(size_t)i1 * FEAT + lane]);
            const float v2 = __half2float(hn[(size_t)i2 * FEAT + lane]);
            const float v3 = __half2float(hn[(size_t)i3 * FEAT + lane]);
            s1a += v0; s2a += v0 * v0; mx = fmaxf(mx, v0); mn = fminf(mn, v0);
            s1b += v1; s2b += v1 * v1; mx = fmaxf(mx, v1); mn = fminf(mn, v1);
            s1c += v2; s2c += v2 * v2; mx = fmaxf(mx, v2); mn = fminf(mn, v2);
            s1d += v3; s2d += v3 * v3; mx = fmaxf(mx, v3); mn = fminf(mn, v3);
            e += 4;
        }
        for (; e < end; ++e) {
            const int s = src[e];
            const float v = __half2float(hn[(size_t)s * FEAT + lane]);
            s1a += v; s2a += v * v; mx = fmaxf(mx, v); mn = fminf(mn, v);
        }
        const float s1 = (s1a + s1b) + (s1c + s1d);
        const float s2 = (s2a + s2b) + (s2c + s2d);
        const float invd = 1.0f / (float)deg;
        const float mean = s1 * invd;
        const float var  = fmaxf(s2 * invd - mean * mean, 0.0f);
        const float stdv = sqrtf(var + EPS_STD);
        const float logD = logf((float)deg + 1.0f);
        const float nrm  = norm[node];
        const float factor = nrm * (1.0f + logD * (1.0f / AVG_D_LOG) + AVG_D_LOG / logD)
                                 * (1.0f / 13.0f);
        pre = hnv * (1.0f / 13.0f) + (mean + mx + mn + stdv) * factor;
    } else {
        pre = hnv * (1.0f / 13.0f);
    }
    out1[(size_t)node * FEAT + lane] = fmaxf(pre, 0.0f);
}

__global__ void __launch_bounds__(256) bn_partial(
    const float* __restrict__ out1,
    double* __restrict__ psum, double* __restrict__ psumsq)
{
    const int tid = threadIdx.x;
    const int fb  = tid & 15;
    const int grp = tid >> 4;
    double s0 = 0, s1 = 0, s2 = 0, s3 = 0;
    double q0 = 0, q1 = 0, q2 = 0, q3 = 0;
    for (int n = blockIdx.x * 16 + grp; n < N_NODES; n += RED_BLOCKS * 16) {
        float4 v = *reinterpret_cast<const float4*>(out1 + (size_t)n * FEAT + fb * 4);
        s0 += (double)v.x; q0 += (double)v.x * (double)v.x;
        s1 += (double)v.y; q1 += (double)v.y * (double)v.y;
        s2 += (double)v.z; q2 += (double)v.z * (double)v.z;
        s3 += (double)v.w; q3 += (double)v.w * (double)v.w;
    }
    __shared__ double ls[256 * 4];
    __shared__ double lq[256 * 4];
    ls[tid * 4 + 0] = s0; ls[tid * 4 + 1] = s1; ls[tid * 4 + 2] = s2; ls[tid * 4 + 3] = s3;
    lq[tid * 4 + 0] = q0; lq[tid * 4 + 1] = q1; lq[tid * 4 + 2] = q2; lq[tid * 4 + 3] = q3;
    __syncthreads();
    if (tid < 64) {
        const int f = tid, fblk = f >> 2, j = f & 3;
        double S = 0, Q = 0;
        for (int g = 0; g < 16; ++g) {
            S += ls[(g * 16 + fblk) * 4 + j];
            Q += lq[(g * 16 + fblk) * 4 + j];
        }
        psum  [blockIdx.x * 64 + f] = S;
        psumsq[blockIdx.x * 64 + f] = Q;
    }
}

__global__ void bn_finalize(const double* __restrict__ psum,
                            const double* __restrict__ psumsq,
                            const float* __restrict__ w, const float* __restrict__ b,
                            float* __restrict__ scale, float* __restrict__ shift)
{
    int f = threadIdx.x;
    double s = 0.0, s2 = 0.0;
    for (int blk = 0; blk < RED_BLOCKS; ++blk) {
        s  += psum  [blk * 64 + f];
        s2 += psumsq[blk * 64 + f];
    }
    double mu   = s / (double)N_NODES;
    double var  = s2 / (double)N_NODES - mu * mu;
    double rstd = 1.0 / sqrt(var + EPS_BN);
    float sc = (float)rstd * w[f];
    scale[f] = sc;
    shift[f] = b[f] - (float)mu * sc;
}

__global__ void __launch_bounds__(256) bn_apply(
    float* __restrict__ out,
    const float* __restrict__ scale, const float* __restrict__ shift)
{
    const size_t i4 = ((size_t)blockIdx.x * blockDim.x + threadIdx.x) * 4;
    if (i4 >= (size_t)N_NODES * FEAT) return;
    float4 v = *reinterpret_cast<const float4*>(out + i4);
    const int f = (int)(i4 & 63);
    v.x = v.x * scale[f + 0] + shift[f + 0];
    v.y = v.y * scale[f + 1] + shift[f + 1];
    v.z = v.z * scale[f + 2] + shift[f + 2];
    v.w = v.w * scale[f + 3] + shift[f + 3];
    *reinterpret_cast<float4*>(out + i4) = v;
}

// ---------------------------------------------------------------------------
extern "C" void kernel_launch(void* const* d_in, const int* in_sizes, int n_in,
                              void* d_out, int out_size, void* d_ws, size_t ws_size,
                              hipStream_t stream) {
    const float* h    = (const float*)d_in[0];
    const float* norm = (const float*)d_in[1];
    /* d_in[2] = e, unused */
    const float* bnw  = (const float*)d_in[3];
    const float* bnb  = (const float*)d_in[4];
    const int*   src  = (const int*)d_in[5];
    const int*   dst  = (const int*)d_in[6];
    float* out = (float*)d_out;

    char* ws = (char*)d_ws;
    // layout: [hn fp16][rowptr][psum(GRID_MAX*64 f64)][psumsq][scale][shift]
    size_t o = 0;
    __half* hnbuf = (__half*)(ws + o);
    o += (((size_t)N_NODES * FEAT * sizeof(__half)) + 255) & ~(size_t)255;   // 12.8 MB
    int* rowptr = (int*)(ws + o);
    o += (((size_t)(N_NODES + 1) * sizeof(int)) + 255) & ~(size_t)255;
    double* psum = (double*)(ws + o);
    o += (size_t)GRID_MAX * 64 * sizeof(double);                              // 1 MB
    double* psumsq = (double*)(ws + o);
    o += (size_t)GRID_MAX * 64 * sizeof(double);                              // 1 MB
    float* scale = (float*)(ws + o); o += 256;
    float* shift = (float*)(ws + o); o += 256;
    const size_t need = o;

    bool coop_ok = (ws_size >= need);
    int grid = 0;
    if (coop_ok) {
        int maxPerCU = 0;
        hipError_t qe = hipOccupancyMaxActiveBlocksPerMultiprocessor(
            &maxPerCU, (const void*)pna_fused, 256, 0);
        if (qe != hipSuccess || maxPerCU < 1) coop_ok = false;
        else {
            grid = maxPerCU * 256;          // 256 CUs on MI355X
            if (grid > GRID_MAX) grid = GRID_MAX;
            if (grid < 64) coop_ok = false; // phase 2 needs >= 64 blocks
        }
    }

    if (coop_ok) {
        void* args[] = { (void*)&h, (void*)&norm, (void*)&bnw, (void*)&bnb,
                         (void*)&src, (void*)&dst, (void*)&out,
                         (void*)&hnbuf, (void*)&rowptr,
                         (void*)&psum, (void*)&psumsq,
                         (void*)&scale, (void*)&shift };
        hipError_t le = hipLaunchCooperativeKernel(
            (const void*)pna_fused, dim3(grid), dim3(256), args, 0, stream);
        if (le == hipSuccess) return;
        /* else fall through to multi-kernel path */
    }

    // ---------------- fallback: proven 5-kernel pipeline ----------------
    hn_rowptr<<<HN_BLOCKS + RP_BLOCKS, 256, 0, stream>>>(h, norm, dst, hnbuf, rowptr);
    pna_agg_fast<<<(N_NODES + 3) / 4, 256, 0, stream>>>(hnbuf, norm, src, rowptr, out);
    bn_partial<<<RED_BLOCKS, 256, 0, stream>>>(out, psum, psumsq);   // uses first 512*64 of psum
    bn_finalize<<<1, 64, 0, stream>>>(psum, psumsq, bnw, bnb, scale, shift);
    bn_apply<<<((N_NODES * FEAT / 4) + 255) / 256, 256, 0, stream>>>(out, scale, shift);
}

// Round 6
// 109.910 us; speedup vs baseline: 4.4455x; 4.4455x over previous
//
#include <hip/hip_runtime.h>
#include <hip/hip_fp16.h>
#include <math.h>
#include <float.h>

#define N_NODES 100000
#define N_EDGES 1200000
#define FEAT 64
#define AVG_D_LOG 2.5649493574615367f  /* log(13.0) */
#define EPS_STD 1e-5f
#define EPS_BN 1e-5
#define AGG_BLOCKS 25000               /* 4 nodes/block, exact: 25000*4 = N_NODES */
#define HN_BLOCKS 6250                 /* N_NODES*FEAT/4/256 */
#define RP_BLOCKS 391                  /* ceil((N_NODES+1)/256) */
#define RED_BLOCKS 512                 /* fallback path */

static __device__ __forceinline__ __half2 shfl_xor_h2(__half2 v, int m) {
    int i; __builtin_memcpy(&i, &v, 4);
    i = __shfl_xor(i, m, 64);
    __half2 r; __builtin_memcpy(&r, &i, 4);
    return r;
}

// ROCm 7.2 hip_fp16.h lacks __hmax2/__hmin2 — use the HW packed ops directly.
static __device__ __forceinline__ __half2 h2max(__half2 a, __half2 b) {
    unsigned ia, ib, ir;
    __builtin_memcpy(&ia, &a, 4); __builtin_memcpy(&ib, &b, 4);
    asm("v_pk_max_f16 %0, %1, %2" : "=v"(ir) : "v"(ia), "v"(ib));
    __half2 r; __builtin_memcpy(&r, &ir, 4);
    return r;
}
static __device__ __forceinline__ __half2 h2min(__half2 a, __half2 b) {
    unsigned ia, ib, ir;
    __builtin_memcpy(&ia, &a, 4); __builtin_memcpy(&ib, &b, 4);
    asm("v_pk_min_f16 %0, %1, %2" : "=v"(ir) : "v"(ia), "v"(ib));
    __half2 r; __builtin_memcpy(&r, &ir, 4);
    return r;
}

// ----------------------------------------------- fused hn(fp16) + rowptr ----
__global__ void __launch_bounds__(256) hn_rowptr(
    const float* __restrict__ h, const float* __restrict__ norm,
    const int* __restrict__ dst,
    __half* __restrict__ hn_h, int* __restrict__ rowptr)
{
    const int b = blockIdx.x;
    if (b < HN_BLOCKS) {
        const size_t i4 = ((size_t)b * 256 + threadIdx.x) * 4;
        const int node = (int)(i4 >> 6);
        const float nr = norm[node];
        float4 v = *reinterpret_cast<const float4*>(h + i4);
        __half2 p0 = __floats2half2_rn(v.x * nr, v.y * nr);
        __half2 p1 = __floats2half2_rn(v.z * nr, v.w * nr);
        __half2* o = reinterpret_cast<__half2*>(hn_h + i4);
        o[0] = p0; o[1] = p1;
    } else {
        const int n = (b - HN_BLOCKS) * 256 + threadIdx.x;
        if (n > N_NODES) return;
        int lo = 0, hi = N_EDGES;
        while (lo < hi) {
            int mid = (lo + hi) >> 1;
            if (dst[mid] < n) lo = mid + 1; else hi = mid;
        }
        rowptr[n] = lo;
    }
}

// ------------------------------------------------------- aggregation --------
// One wave per node. Lane sub=lane&31 owns features (2sub, 2sub+1) as half2;
// half-wave 0 processes even edges, half-wave 1 odd edges; combine via
// shfl_xor(32). Packed fp16 accumulate (hadd2/hfma2/pk_max/pk_min).
template <bool WRITE_PSTAT>
__global__ void __launch_bounds__(256) pna_agg2(
    const __half* __restrict__ hn, const float* __restrict__ norm,
    const int* __restrict__ src, const int* __restrict__ rowptr,
    float* __restrict__ out, __half2* __restrict__ pstat)
{
    const int tid    = threadIdx.x;
    const int wid    = tid >> 6;
    const int lane   = tid & 63;
    const int sub    = lane & 31;
    const int halfId = lane >> 5;
    const int node   = blockIdx.x * 4 + wid;           // always < N_NODES

    const int start = __builtin_amdgcn_readfirstlane(rowptr[node]);
    const int end   = __builtin_amdgcn_readfirstlane(rowptr[node + 1]);
    const int deg   = end - start;

    const __half2 ownh = *reinterpret_cast<const __half2*>(hn + (size_t)node * FEAT + 2 * sub);
    const float hnv0 = __low2float(ownh);
    const float hnv1 = __high2float(ownh);

    float v0, v1;
    if (deg > 0) {
        __half2 s1 = __float2half2_rn(0.f);
        __half2 s2 = __float2half2_rn(0.f);
        __half2 mx = __float2half2_rn(-65504.f);
        __half2 mn = __float2half2_rn(65504.f);
        int e = start;
#define GATHER(J) (*reinterpret_cast<const __half2*>(hn + (size_t)(J) * FEAT + 2 * sub))
#define ACC(W) do { __half2 w_ = (W); s1 = __hadd2(s1, w_); s2 = __hfma2(w_, w_, s2); \
                    mx = h2max(mx, w_); mn = h2min(mn, w_); } while (0)
        for (; e + 8 <= end; e += 8) {                 // 4 pairs = 8 edges in flight
            const int a0 = src[e + 0], b0 = src[e + 1];
            const int a1 = src[e + 2], b1 = src[e + 3];
            const int a2 = src[e + 4], b2 = src[e + 5];
            const int a3 = src[e + 6], b3 = src[e + 7];
            const int j0 = halfId ? b0 : a0;
            const int j1 = halfId ? b1 : a1;
            const int j2 = halfId ? b2 : a2;
            const int j3 = halfId ? b3 : a3;
            __half2 w0 = GATHER(j0), w1 = GATHER(j1), w2 = GATHER(j2), w3 = GATHER(j3);
            ACC(w0); ACC(w1); ACC(w2); ACC(w3);
        }
        if (e + 4 <= end) {                            // 2 pairs
            const int a0 = src[e + 0], b0 = src[e + 1];
            const int a1 = src[e + 2], b1 = src[e + 3];
            const int j0 = halfId ? b0 : a0;
            const int j1 = halfId ? b1 : a1;
            __half2 w0 = GATHER(j0), w1 = GATHER(j1);
            ACC(w0); ACC(w1);
            e += 4;
        }
        if (e + 2 <= end) {                            // 1 pair
            const int a = src[e], b = src[e + 1];
            const int j = halfId ? b : a;
            __half2 w = GATHER(j);
            ACC(w);
            e += 2;
        }
        if (e < end) {                                 // odd last edge: half 0 only
            const int j = src[e];
            __half2 w = GATHER(j);
            if (halfId == 0) ACC(w);
        }
#undef ACC
#undef GATHER
        // combine the two half-wave partials (lane <-> lane^32)
        s1 = __hadd2(s1, shfl_xor_h2(s1, 32));
        s2 = __hadd2(s2, shfl_xor_h2(s2, 32));
        mx = h2max(mx, shfl_xor_h2(mx, 32));
        mn = h2min(mn, shfl_xor_h2(mn, 32));

        const float invd = 1.0f / (float)deg;
        const float mean0 = __low2float(s1) * invd, mean1 = __high2float(s1) * invd;
        const float var0 = fmaxf(__low2float(s2)  * invd - mean0 * mean0, 0.f);
        const float var1 = fmaxf(__high2float(s2) * invd - mean1 * mean1, 0.f);
        const float std0 = sqrtf(var0 + EPS_STD), std1 = sqrtf(var1 + EPS_STD);
        const float logD = logf((float)deg + 1.0f);
        const float nrm  = norm[node];
        const float factor = nrm * (1.0f + logD * (1.0f / AVG_D_LOG) + AVG_D_LOG / logD)
                                 * (1.0f / 13.0f);
        v0 = fmaxf(hnv0 * (1.0f / 13.0f) + (mean0 + __low2float(mx)  + __low2float(mn)  + std0) * factor, 0.f);
        v1 = fmaxf(hnv1 * (1.0f / 13.0f) + (mean1 + __high2float(mx) + __high2float(mn) + std1) * factor, 0.f);
    } else {
        v0 = fmaxf(hnv0 * (1.0f / 13.0f), 0.f);
        v1 = fmaxf(hnv1 * (1.0f / 13.0f), 0.f);
    }

    if (halfId == 0) {
        float2 st; st.x = v0; st.y = v1;
        *reinterpret_cast<float2*>(out + (size_t)node * FEAT + 2 * sub) = st;
    }

    if (WRITE_PSTAT) {
        __shared__ float lsS[4][64];
        __shared__ float lsQ[4][64];
        if (halfId == 0) {
            lsS[wid][2 * sub] = v0; lsS[wid][2 * sub + 1] = v1;
            lsQ[wid][2 * sub] = v0 * v0; lsQ[wid][2 * sub + 1] = v1 * v1;
        }
        __syncthreads();
        if (tid < 64) {
            float S = lsS[0][tid] + lsS[1][tid] + lsS[2][tid] + lsS[3][tid];
            float Q = lsQ[0][tid] + lsQ[1][tid] + lsQ[2][tid] + lsQ[3][tid];
            pstat[(size_t)blockIdx.x * 64 + tid] = __floats2half2_rn(S, Q);
        }
    }
}

// ---------------------------------------- BN finalize (64 blocks, 1/feature)
__global__ void __launch_bounds__(256) bn_finalize2(
    const __half2* __restrict__ pstat,
    const float* __restrict__ w, const float* __restrict__ b,
    float2* __restrict__ ss)
{
    const int f   = (int)blockIdx.x;                   // 0..63
    const int tid = threadIdx.x;
    float S = 0.f, Q = 0.f;
    for (int blk = tid; blk < AGG_BLOCKS; blk += 256) {
        __half2 p = pstat[(size_t)blk * 64 + f];
        S += __low2float(p); Q += __high2float(p);
    }
    __shared__ double rs[256], rq[256];
    rs[tid] = (double)S; rq[tid] = (double)Q;
    __syncthreads();
    for (int s = 128; s > 0; s >>= 1) {
        if (tid < s) { rs[tid] += rs[tid + s]; rq[tid] += rq[tid + s]; }
        __syncthreads();
    }
    if (tid == 0) {
        double mu   = rs[0] / (double)N_NODES;
        double var  = rq[0] / (double)N_NODES - mu * mu;
        double rstd = 1.0 / sqrt(var + EPS_BN);
        float sc = (float)rstd * w[f];
        float2 o; o.x = sc; o.y = b[f] - (float)mu * sc;
        ss[f] = o;
    }
}

// -------------------------------------------- fallback BN stats (proven) ----
__global__ void __launch_bounds__(256) bn_partial(
    const float* __restrict__ out1,
    double* __restrict__ psum, double* __restrict__ psumsq)
{
    const int tid = threadIdx.x;
    const int fb  = tid & 15;
    const int grp = tid >> 4;
    double s0 = 0, s1 = 0, s2 = 0, s3 = 0;
    double q0 = 0, q1 = 0, q2 = 0, q3 = 0;
    for (int n = blockIdx.x * 16 + grp; n < N_NODES; n += RED_BLOCKS * 16) {
        float4 v = *reinterpret_cast<const float4*>(out1 + (size_t)n * FEAT + fb * 4);
        s0 += (double)v.x; q0 += (double)v.x * (double)v.x;
        s1 += (double)v.y; q1 += (double)v.y * (double)v.y;
        s2 += (double)v.z; q2 += (double)v.z * (double)v.z;
        s3 += (double)v.w; q3 += (double)v.w * (double)v.w;
    }
    __shared__ double ls[256 * 4];
    __shared__ double lq[256 * 4];
    ls[tid * 4 + 0] = s0; ls[tid * 4 + 1] = s1; ls[tid * 4 + 2] = s2; ls[tid * 4 + 3] = s3;
    lq[tid * 4 + 0] = q0; lq[tid * 4 + 1] = q1; lq[tid * 4 + 2] = q2; lq[tid * 4 + 3] = q3;
    __syncthreads();
    if (tid < 64) {
        const int f = tid, fblk = f >> 2, j = f & 3;
        double S = 0, Q = 0;
        for (int g = 0; g < 16; ++g) {
            S += ls[(g * 16 + fblk) * 4 + j];
            Q += lq[(g * 16 + fblk) * 4 + j];
        }
        psum  [blockIdx.x * 64 + f] = S;
        psumsq[blockIdx.x * 64 + f] = Q;
    }
}

__global__ void bn_finalize_old(const double* __restrict__ psum,
                                const double* __restrict__ psumsq,
                                const float* __restrict__ w, const float* __restrict__ b,
                                float2* __restrict__ ss)
{
    int f = threadIdx.x;                               // 64 threads
    double s = 0.0, s2 = 0.0;
    for (int blk = 0; blk < RED_BLOCKS; ++blk) {
        s  += psum  [blk * 64 + f];
        s2 += psumsq[blk * 64 + f];
    }
    double mu   = s / (double)N_NODES;
    double var  = s2 / (double)N_NODES - mu * mu;
    double rstd = 1.0 / sqrt(var + EPS_BN);
    float sc = (float)rstd * w[f];
    float2 o; o.x = sc; o.y = b[f] - (float)mu * sc;
    ss[f] = o;
}

// ------------------------------------------------------- BN apply -----------
__global__ void __launch_bounds__(256) bn_apply2(
    float* __restrict__ out, const float2* __restrict__ ss)
{
    __shared__ float sS[64], sH[64];
    if (threadIdx.x < 64) {
        float2 p = ss[threadIdx.x];
        sS[threadIdx.x] = p.x; sH[threadIdx.x] = p.y;
    }
    __syncthreads();
    const size_t i4 = ((size_t)blockIdx.x * 256 + threadIdx.x) * 4;   // grid exact
    float4 v = *reinterpret_cast<const float4*>(out + i4);
    const int f = (int)(i4 & 63);
    v.x = v.x * sS[f + 0] + sH[f + 0];
    v.y = v.y * sS[f + 1] + sH[f + 1];
    v.z = v.z * sS[f + 2] + sH[f + 2];
    v.w = v.w * sS[f + 3] + sH[f + 3];
    *reinterpret_cast<float4*>(out + i4) = v;
}

// ---------------------------------------------------------------------------
extern "C" void kernel_launch(void* const* d_in, const int* in_sizes, int n_in,
                              void* d_out, int out_size, void* d_ws, size_t ws_size,
                              hipStream_t stream) {
    const float* h    = (const float*)d_in[0];
    const float* norm = (const float*)d_in[1];
    /* d_in[2] = e, unused */
    const float* bnw  = (const float*)d_in[3];
    const float* bnb  = (const float*)d_in[4];
    const int*   src  = (const int*)d_in[5];
    const int*   dst  = (const int*)d_in[6];
    float* out = (float*)d_out;

    char* ws = (char*)d_ws;
    size_t o = 0;
    __half* hnbuf = (__half*)(ws + o);
    o += (((size_t)N_NODES * FEAT * sizeof(__half)) + 255) & ~(size_t)255;    // 12.8 MB
    int* rowptr = (int*)(ws + o);
    o += (((size_t)(N_NODES + 1) * sizeof(int)) + 255) & ~(size_t)255;        // 0.4 MB
    float2* ss = (float2*)(ws + o);
    o += 256;                                                                  // scale/shift
    // new path: pstat half2 [AGG_BLOCKS][64]
    __half2* pstat = (__half2*)(ws + o);
    const size_t need_new = o + (size_t)AGG_BLOCKS * 64 * sizeof(__half2);     // +6.4 MB
    // fallback path: psum/psumsq doubles
    double* psum   = (double*)(ws + o);
    double* psumsq = (double*)(ws + o + (size_t)RED_BLOCKS * 64 * sizeof(double));

    hn_rowptr<<<HN_BLOCKS + RP_BLOCKS, 256, 0, stream>>>(h, norm, dst, hnbuf, rowptr);

    if (ws_size >= need_new) {
        pna_agg2<true><<<AGG_BLOCKS, 256, 0, stream>>>(hnbuf, norm, src, rowptr, out, pstat);
        bn_finalize2<<<64, 256, 0, stream>>>(pstat, bnw, bnb, ss);
    } else {
        pna_agg2<false><<<AGG_BLOCKS, 256, 0, stream>>>(hnbuf, norm, src, rowptr, out, nullptr);
        bn_partial<<<RED_BLOCKS, 256, 0, stream>>>(out, psum, psumsq);
        bn_finalize_old<<<1, 64, 0, stream>>>(psum, psumsq, bnw, bnb, ss);
    }
    bn_apply2<<<HN_BLOCKS, 256, 0, stream>>>(out, ss);
}